// Round 12
// baseline (1911.619 us; speedup 1.0000x reference)
//
#include <hip/hip_runtime.h>
#include <hip/hip_bf16.h>

#define HDIM 256
#define ATOMF 133
#define BONDF 14
#define DEPTH_HC 4
#define SCAN_CHUNK 1024
#define KWN 416   // Wn GEMM K: atomb [0,160), M [160,416)

typedef short bf16x8 __attribute__((ext_vector_type(8)));
typedef float f32x4 __attribute__((ext_vector_type(4)));
typedef unsigned short u16x8 __attribute__((ext_vector_type(8)));
typedef unsigned short u16x4 __attribute__((ext_vector_type(4)));

__device__ inline float bf2f(unsigned short u) {
    unsigned int x = ((unsigned int)u) << 16;
    float f; __builtin_memcpy(&f, &x, 4); return f;
}
__device__ inline unsigned short f2bf(float f) {
    __hip_bfloat16 h = __float2bfloat16(f);
    unsigned short u; __builtin_memcpy(&u, &h, 2); return u;
}

__device__ inline void gload_lds16(const unsigned short* g, unsigned short* lds) {
    __builtin_amdgcn_global_load_lds(
        (const __attribute__((address_space(1))) unsigned int*)g,
        (__attribute__((address_space(3))) unsigned int*)lds, 16, 0, 0);
}

// common MFMA step: compute 4x4 accumulators from As/Bs buffers
#define MFMA_STEP(ASB, BSB)                                                        \
    {                                                                              \
        const int kq = (l >> 4) * 8;                                               \
        const int rbase = (wr << 6) + (l & 15);                                    \
        const int cbase = (wc << 6) + (l & 15);                                    \
        bf16x8 af[4], bfr[4];                                                      \
        _Pragma("unroll")                                                          \
        for (int i = 0; i < 4; ++i) {                                              \
            af[i]  = *(const bf16x8*)&(ASB)[(rbase + i * 16) * 32 + kq];           \
            bfr[i] = *(const bf16x8*)&(BSB)[(cbase + i * 16) * 32 + kq];           \
        }                                                                          \
        _Pragma("unroll")                                                          \
        for (int mi = 0; mi < 4; ++mi)                                             \
            _Pragma("unroll")                                                      \
            for (int ni = 0; ni < 4; ++ni)                                         \
                acc[mi][ni] = __builtin_amdgcn_mfma_f32_16x16x32_bf16(             \
                    af[mi], bfr[ni], acc[mi][ni], 0, 0, 0);                        \
    }

// ========== fused cat+GEMM1: h0 = relu([atomb[src[e]]|bond-overlay] @ Wi^T), K=160 ==========
__global__ __launch_bounds__(512) void mfma_gemm_cat(
    const unsigned short* __restrict__ atomb,  // [N][160] bf16, zero-padded
    const float* __restrict__ bond,
    const int* __restrict__ src, int E,
    const unsigned short* __restrict__ W,      // Wib [256][160] bf16
    unsigned short* __restrict__ Cb)           // h [E][256]
{
    __shared__ unsigned short As[2][128 * 32];
    __shared__ unsigned short Bs[2][256 * 32];
    const int t = threadIdx.x;
    const int w = t >> 6, l = t & 63;
    const int m0 = blockIdx.x * 128;
    const int wr = w >> 2, wc = w & 3;

    f32x4 acc[4][4] = {};

    const int ar = t >> 2;
    const int ac0 = (t & 3) * 8;
    long long e_row = m0 + ar; if (e_row > E - 1) e_row = E - 1;
    const int sn = src[e_row];
    const unsigned short* arow = atomb + (size_t)sn * 160;
    const float* brow = bond + (size_t)e_row * BONDF;

    // tail chunk (chunk 4, cols 128..159): atom[128,133) | bond | zeros
    u16x8 tail = *(const u16x8*)&arow[128 + ac0];
    #pragma unroll
    for (int i = 0; i < 8; ++i) {
        int k = 128 + ac0 + i;
        if (k >= ATOMF && k < ATOMF + BONDF) tail[i] = f2bf(brow[k - ATOMF]);
    }

    const int kcol = (l & 3) * 8;
    const int rowL = (w << 4) + (l >> 2);

    {
        u16x8 o = *(const u16x8*)&arow[ac0];
        *(u16x8*)&As[0][ar * 32 + ac0] = o;
        gload_lds16(W + (size_t)rowL * 160 + kcol, Bs[0] + (size_t)w * 512);
        gload_lds16(W + (size_t)(128 + rowL) * 160 + kcol, Bs[0] + 4096 + (size_t)w * 512);
    }
    u16x8 regs = *(const u16x8*)&arow[32 + ac0];   // chunk 1
    __syncthreads();

    #pragma unroll
    for (int c = 0; c < 5; ++c) {      // k0 = c*32, K=160
        const int cb = c & 1, nb = cb ^ 1;
        if (c + 1 < 5) {
            u16x8 o = (c + 1 == 4) ? tail : regs;
            *(u16x8*)&As[nb][ar * 32 + ac0] = o;
            gload_lds16(W + (size_t)rowL * 160 + (c + 1) * 32 + kcol, Bs[nb] + (size_t)w * 512);
            gload_lds16(W + (size_t)(128 + rowL) * 160 + (c + 1) * 32 + kcol,
                        Bs[nb] + 4096 + (size_t)w * 512);
            if (c + 2 < 4) regs = *(const u16x8*)&arow[(c + 2) * 32 + ac0];
        }
        MFMA_STEP(As[cb], Bs[cb]);
        __syncthreads();
    }

    const int ccol = l & 15, crow = (l >> 4) * 4;
    #pragma unroll
    for (int ni = 0; ni < 4; ++ni) {
        int gn = (wc << 6) + ni * 16 + ccol;
        #pragma unroll
        for (int mi = 0; mi < 4; ++mi) {
            #pragma unroll
            for (int j = 0; j < 4; ++j) {
                long long gm = m0 + (wr << 6) + mi * 16 + crow + j;
                if (gm >= E) continue;
                float v = fmaxf(acc[mi][ni][j], 0.0f);
                Cb[(size_t)gm * HDIM + gn] = f2bf(v);
            }
        }
    }
}

// ========== fused msg+GEMM, IN-PLACE, counted-vmcnt single-barrier schedule ==========
// h[e] <- relu((M[src[e]] - w[e^1]h[e^1]) @ Wm^T + b).  One s_barrier per K-chunk;
// W prefetch window = 2 chunks (vmcnt(2), never 0 in steady state); A-regs 2 chunks deep.
__global__ __launch_bounds__(512) void mfma_gemm_msg(
    const unsigned short* __restrict__ Mb,  // [N][256] bf16
    unsigned short* h,                      // [E][256] bf16, read+written in place
    const float* __restrict__ w,
    const int* __restrict__ src, int E,
    const unsigned short* __restrict__ W,   // Wmb [256][256] bf16
    const float* __restrict__ bias,         // Wm_b
    float* __restrict__ Cf)                 // h_f32 (last iter) or null
{
    __shared__ unsigned short As[2][128 * 32];
    __shared__ unsigned short Bs[2][256 * 32];
    const int t = threadIdx.x;
    const int wv = t >> 6, l = t & 63;
    const int m0 = blockIdx.x * 128;
    const int wr = wv >> 2, wc = wv & 3;

    f32x4 acc[4][4] = {};

    const int ar = t >> 2;
    const int ac0 = (t & 3) * 8;
    long long e_row = m0 + ar; if (e_row > E - 1) e_row = E - 1;
    const long long er1 = e_row ^ 1;
    const int sn = src[e_row];
    const float we1 = w[er1];
    const unsigned short* mrow = Mb + (size_t)sn * HDIM;
    const unsigned short* hrow = h + (size_t)er1 * HDIM;

    const int kcol = (l & 3) * 8;
    const int rowL = (wv << 4) + (l >> 2);

    // ---- prologue: build A(0),A(1); gload W(0),W(1); preload A-regs chunks 2,3 ----
    {
        u16x8 M0 = *(const u16x8*)&mrow[ac0];
        u16x8 h0 = *(const u16x8*)&hrow[ac0];
        u16x8 M1 = *(const u16x8*)&mrow[32 + ac0];
        u16x8 h1 = *(const u16x8*)&hrow[32 + ac0];
        u16x8 o0, o1;
        #pragma unroll
        for (int i = 0; i < 8; ++i) {
            o0[i] = f2bf(bf2f(M0[i]) - we1 * bf2f(h0[i]));
            o1[i] = f2bf(bf2f(M1[i]) - we1 * bf2f(h1[i]));
        }
        *(u16x8*)&As[0][ar * 32 + ac0] = o0;
        *(u16x8*)&As[1][ar * 32 + ac0] = o1;
        gload_lds16(W + (size_t)rowL * 256 + kcol, Bs[0] + (size_t)wv * 512);
        gload_lds16(W + (size_t)(128 + rowL) * 256 + kcol, Bs[0] + 4096 + (size_t)wv * 512);
        gload_lds16(W + (size_t)rowL * 256 + 32 + kcol, Bs[1] + (size_t)wv * 512);
        gload_lds16(W + (size_t)(128 + rowL) * 256 + 32 + kcol, Bs[1] + 4096 + (size_t)wv * 512);
    }
    u16x8 Mra = *(const u16x8*)&mrow[64 + ac0];   // chunk 2 (even-parity set)
    u16x8 hra = *(const u16x8*)&hrow[64 + ac0];
    u16x8 Mrb = *(const u16x8*)&mrow[96 + ac0];   // chunk 3 (odd-parity set)
    u16x8 hrb = *(const u16x8*)&hrow[96 + ac0];
    asm volatile("s_waitcnt lgkmcnt(0)" ::: "memory");
    asm volatile("s_waitcnt vmcnt(4)" ::: "memory");   // W(0),W(1) landed; A-regs 2,3 in flight
    __builtin_amdgcn_sched_barrier(0);
    __builtin_amdgcn_s_barrier();
    asm volatile("" ::: "memory");
    __builtin_amdgcn_sched_barrier(0);

    const int kq = (l >> 4) * 8;
    const int rbase = (wr << 6) + (l & 15);
    const int cbase = (wc << 6) + (l & 15);

    #pragma unroll
    for (int c = 0; c < 8; ++c) {
        const int cb = c & 1;
        // 1. load fragments for chunk c into regs
        bf16x8 af[4], bfr[4];
        #pragma unroll
        for (int i = 0; i < 4; ++i) {
            af[i]  = *(const bf16x8*)&As[cb][(rbase + i * 16) * 32 + kq];
            bfr[i] = *(const bf16x8*)&Bs[cb][(cbase + i * 16) * 32 + kq];
        }
        // 2. own ds_reads + own prior ds_writes drained
        asm volatile("s_waitcnt lgkmcnt(0)" ::: "memory");
        __builtin_amdgcn_sched_barrier(0);
        // 3. counted vmcnt: W(c+1) landed (c<=4: 2 newest = A-regs(c+3); else drain)
        if (c <= 4) { asm volatile("s_waitcnt vmcnt(2)" ::: "memory"); }
        else        { asm volatile("s_waitcnt vmcnt(0)" ::: "memory"); }
        __builtin_amdgcn_sched_barrier(0);
        // 4. single barrier: [cb] consumed by all; [nb] staged+visible for next step
        __builtin_amdgcn_s_barrier();
        asm volatile("" ::: "memory");
        __builtin_amdgcn_sched_barrier(0);
        // 5. stage chunk c+2 into the just-freed [cb]; issue A-reg loads for c+4
        if (c + 2 < 8) {
            u16x8 Mu = (c & 1) ? Mrb : Mra;
            u16x8 hu = (c & 1) ? hrb : hra;
            u16x8 o;
            #pragma unroll
            for (int i = 0; i < 8; ++i) o[i] = f2bf(bf2f(Mu[i]) - we1 * bf2f(hu[i]));
            *(u16x8*)&As[cb][ar * 32 + ac0] = o;
            gload_lds16(W + (size_t)rowL * 256 + (c + 2) * 32 + kcol,
                        Bs[cb] + (size_t)wv * 512);
            gload_lds16(W + (size_t)(128 + rowL) * 256 + (c + 2) * 32 + kcol,
                        Bs[cb] + 4096 + (size_t)wv * 512);
            if (c + 4 < 8) {
                if (c & 1) {
                    Mrb = *(const u16x8*)&mrow[(c + 4) * 32 + ac0];
                    hrb = *(const u16x8*)&hrow[(c + 4) * 32 + ac0];
                } else {
                    Mra = *(const u16x8*)&mrow[(c + 4) * 32 + ac0];
                    hra = *(const u16x8*)&hrow[(c + 4) * 32 + ac0];
                }
            }
        }
        // 6. MFMA for chunk c (register operands only)
        #pragma unroll
        for (int mi = 0; mi < 4; ++mi)
            #pragma unroll
            for (int ni = 0; ni < 4; ++ni)
                acc[mi][ni] = __builtin_amdgcn_mfma_f32_16x16x32_bf16(
                    af[mi], bfr[ni], acc[mi][ni], 0, 0, 0);
    }
    // all h reads of this tile complete -> in-place write safe

    const int ccol = l & 15, crow = (l >> 4) * 4;
    #pragma unroll
    for (int ni = 0; ni < 4; ++ni) {
        int gn = (wc << 6) + ni * 16 + ccol;
        float bv = bias[gn];
        #pragma unroll
        for (int mi = 0; mi < 4; ++mi) {
            #pragma unroll
            for (int j = 0; j < 4; ++j) {
                long long gm = m0 + (wr << 6) + mi * 16 + crow + j;
                if (gm >= E) continue;
                float v = fmaxf(acc[mi][ni][j] + bv, 0.0f);
                if (Cf) Cf[(size_t)gm * HDIM + gn] = v;
                h[(size_t)gm * HDIM + gn] = f2bf(v);
            }
        }
    }
}

// ========== fused cat+Wn GEMM: node_repr = relu([atomb[n]|Mb[n]] @ Wnb^T + b), K=416 ==========
__global__ __launch_bounds__(512) void mfma_gemm_catwn(
    const unsigned short* __restrict__ atomb,  // [N][160] bf16 zero-padded
    const unsigned short* __restrict__ Mb,     // [N][256] bf16
    int N,
    const unsigned short* __restrict__ W,      // Wnb [256][416] bf16
    const float* __restrict__ bias,            // Wn_b
    float* __restrict__ Cf,                    // node_repr f32 [N][256]
    unsigned short* __restrict__ Cb)           // node_repr bf16 [N][256]
{
    __shared__ unsigned short As[2][128 * 32];
    __shared__ unsigned short Bs[2][256 * 32];
    const int t = threadIdx.x;
    const int wv = t >> 6, l = t & 63;
    const int m0 = blockIdx.x * 128;
    const int wr = wv >> 2, wc = wv & 3;

    f32x4 acc[4][4] = {};

    const int ar = t >> 2;
    const int ac0 = (t & 3) * 8;
    long long nrow = m0 + ar; if (nrow > N - 1) nrow = N - 1;
    const unsigned short* arow = atomb + (size_t)nrow * 160;
    const unsigned short* mrow = Mb + (size_t)nrow * HDIM;

    const int kcol = (l & 3) * 8;
    const int rowL = (wv << 4) + (l >> 2);

    #define LOADA_WN(c) ((c) < 5 ? *(const u16x8*)&arow[(c) * 32 + ac0] \
                                 : *(const u16x8*)&mrow[(c) * 32 - 160 + ac0])

    {
        u16x8 o = LOADA_WN(0);
        *(u16x8*)&As[0][ar * 32 + ac0] = o;
        gload_lds16(W + (size_t)rowL * KWN + kcol, Bs[0] + (size_t)wv * 512);
        gload_lds16(W + (size_t)(128 + rowL) * KWN + kcol, Bs[0] + 4096 + (size_t)wv * 512);
    }
    u16x8 regs = LOADA_WN(1);
    __syncthreads();

    #pragma unroll
    for (int c = 0; c < 13; ++c) {     // k0 = c*32, K=416
        const int cb = c & 1, nb = cb ^ 1;
        if (c + 1 < 13) {
            *(u16x8*)&As[nb][ar * 32 + ac0] = regs;
            gload_lds16(W + (size_t)rowL * KWN + (c + 1) * 32 + kcol, Bs[nb] + (size_t)wv * 512);
            gload_lds16(W + (size_t)(128 + rowL) * KWN + (c + 1) * 32 + kcol,
                        Bs[nb] + 4096 + (size_t)wv * 512);
            if (c + 2 < 13) regs = LOADA_WN(c + 2);
        }
        MFMA_STEP(As[cb], Bs[cb]);
        __syncthreads();
    }
    #undef LOADA_WN

    const int ccol = l & 15, crow = (l >> 4) * 4;
    #pragma unroll
    for (int ni = 0; ni < 4; ++ni) {
        int gn = (wc << 6) + ni * 16 + ccol;
        float bv = bias[gn];
        #pragma unroll
        for (int mi = 0; mi < 4; ++mi) {
            #pragma unroll
            for (int j = 0; j < 4; ++j) {
                long long gm = m0 + (wr << 6) + mi * 16 + crow + j;
                if (gm >= N) continue;
                float v = fmaxf(acc[mi][ni][j] + bv, 0.0f);
                Cf[(size_t)gm * HDIM + gn] = v;
                Cb[(size_t)gm * HDIM + gn] = f2bf(v);
            }
        }
    }
}

// ========== fused 2-layer head: pred = relu(A@W^T + b0) @ W2^T + b2 (K=256, NOUT2<=144) ==========
__global__ __launch_bounds__(512) void head_fused(
    const unsigned short* __restrict__ A, int Mrows,
    const unsigned short* __restrict__ W,       // [256][256] bf16
    const float* __restrict__ b0,               // [256]
    const unsigned short* __restrict__ W2b,     // [256][256] bf16 (rows = out cols, padded 0)
    const float* __restrict__ b2,               // [NOUT2]
    float* __restrict__ pred, int NOUT2)        // [M][NOUT2]
{
    __shared__ unsigned short R[128 * 256];     // 64KB
    unsigned short* As0 = R;
    unsigned short* As1 = R + 4096;
    unsigned short* Bs0 = R + 8192;
    unsigned short* Bs1 = R + 16384;
    unsigned short* AsB[2] = {As0, As1};
    unsigned short* BsB[2] = {Bs0, Bs1};
    const int t = threadIdx.x;
    const int w = t >> 6, l = t & 63;
    const int m0 = blockIdx.x * 128;
    const int wr = w >> 2, wc = w & 3;
    const int kq = (l >> 4) * 8;

    f32x4 acc[4][4] = {};
    const int kcol = (l & 3) * 8;
    const int rowL = (w << 4) + (l >> 2);
    long long r0 = m0 + rowL; if (r0 > Mrows - 1) r0 = Mrows - 1;

    {
        gload_lds16(A + (size_t)r0 * 256 + kcol, As0 + (size_t)w * 512);
        gload_lds16(W + (size_t)rowL * 256 + kcol, Bs0 + (size_t)w * 512);
        gload_lds16(W + (size_t)(128 + rowL) * 256 + kcol, Bs0 + 4096 + (size_t)w * 512);
    }
    __syncthreads();

    #pragma unroll
    for (int c = 0; c < 8; ++c) {
        const int cb = c & 1, nb = cb ^ 1;
        if (c + 1 < 8) {
            gload_lds16(A + (size_t)r0 * 256 + (c + 1) * 32 + kcol, AsB[nb] + (size_t)w * 512);
            gload_lds16(W + (size_t)rowL * 256 + (c + 1) * 32 + kcol, BsB[nb] + (size_t)w * 512);
            gload_lds16(W + (size_t)(128 + rowL) * 256 + (c + 1) * 32 + kcol,
                        BsB[nb] + 4096 + (size_t)w * 512);
        }
        MFMA_STEP(AsB[cb], BsB[cb]);
        __syncthreads();
    }

    // phase 1: write relu(acc + b0) -> R, XOR-swizzled
    const int ccol = l & 15, crow = (l >> 4) * 4;
    #pragma unroll
    for (int ni = 0; ni < 4; ++ni) {
        const int col = (wc << 6) + ni * 16 + ccol;
        const float bv = b0[col];
        #pragma unroll
        for (int mi = 0; mi < 4; ++mi) {
            #pragma unroll
            for (int j = 0; j < 4; ++j) {
                const int rr = (wr << 6) + mi * 16 + crow + j;
                float v = fmaxf(acc[mi][ni][j] + bv, 0.0f);
                size_t byteoff = ((size_t)rr * 512 + (size_t)col * 2) ^ (size_t)((rr & 7) << 4);
                *(unsigned short*)((char*)R + byteoff) = f2bf(v);
            }
        }
    }
    __syncthreads();

    // phase 2: wave w -> e-rows w*16..+15; loop over 16-col output groups
    const int erow = (w << 4) + (l & 15);
    const int jrow = l & 15;
    for (int cc = 0; cc * 16 < NOUT2; ++cc) {
        bf16x8 w2b[8];
        #pragma unroll
        for (int ks = 0; ks < 8; ++ks)
            w2b[ks] = *(const bf16x8*)&W2b[(size_t)(cc * 16 + jrow) * 256 + ks * 32 + kq];
        f32x4 acc2 = {};
        #pragma unroll
        for (int ks = 0; ks < 8; ++ks) {
            size_t byteoff = ((size_t)erow * 512 + (size_t)(ks * 64 + kq * 2))
                             ^ (size_t)((erow & 7) << 4);
            bf16x8 af;
            __builtin_memcpy(&af, (char*)R + byteoff, 16);
            acc2 = __builtin_amdgcn_mfma_f32_16x16x32_bf16(af, w2b[ks], acc2, 0, 0, 0);
        }
        const int col = cc * 16 + jrow;
        if (col < NOUT2) {
            #pragma unroll
            for (int j = 0; j < 4; ++j) {
                long long gm = m0 + (w << 4) + (l >> 4) * 4 + j;
                if (gm < Mrows) pred[gm * NOUT2 + col] = acc2[j] + b2[col];
            }
        }
    }
}

// ============ atom f32 [N][133] -> bf16 [N][160] zero-padded ============
__global__ __launch_bounds__(640) void atom_conv(const float* __restrict__ a,
                                                 unsigned short* __restrict__ ab, int N) {
    int n = blockIdx.x * 4 + threadIdx.x / 160;
    int c = threadIdx.x % 160;
    if (n >= N) return;
    ab[(size_t)n * 160 + c] = (c < ATOMF) ? f2bf(a[(size_t)n * ATOMF + c]) : (unsigned short)0;
}

// ============ all weight pads in one kernel (7 weights) ============
__global__ void pad_all(const float* Wi, const float* Wm, const float* Wn,
                        const float* n0, const float* n2, const float* e0, const float* e2,
                        unsigned short* Wib, unsigned short* Wmb, unsigned short* Wnb,
                        unsigned short* n0b, unsigned short* n2b, unsigned short* e0b,
                        unsigned short* e2b) {
    int wid = blockIdx.x >> 8;
    int r = blockIdx.x & 255;
    if (wid == 2) {  // Wn [256][389] -> [256][416]: atom cols [0,133), M cols [160,416)
        for (int c = threadIdx.x; c < KWN; c += blockDim.x) {
            float v = 0.0f;
            if (c < ATOMF)      v = Wn[(size_t)r * 389 + c];
            else if (c >= 160)  v = Wn[(size_t)r * 389 + (c - 27)];
            Wnb[(size_t)r * KWN + c] = f2bf(v);
        }
        return;
    }
    const float* S; unsigned short* D; int R, C, Cp;
    switch (wid) {
        case 0: S = Wi; D = Wib; R = 256; C = 147; Cp = 160; break;
        case 1: S = Wm; D = Wmb; R = 256; C = 256; Cp = 256; break;
        case 3: S = n0; D = n0b; R = 256; C = 256; Cp = 256; break;
        case 4: S = n2; D = n2b; R = 133; C = 256; Cp = 256; break;
        case 5: S = e0; D = e0b; R = 256; C = 256; Cp = 256; break;
        default: S = e2; D = e2b; R = 14;  C = 256; Cp = 256; break;
    }
    for (int c = threadIdx.x; c < Cp; c += blockDim.x) {
        float v = (r < R && c < C) ? S[(size_t)r * C + c] : 0.0f;
        D[(size_t)r * Cp + c] = f2bf(v);
    }
}

// ================== CSR build ==================
__global__ void count_dst(const int* __restrict__ dst, int* __restrict__ cnt, int E) {
    int e = blockIdx.x * 256 + threadIdx.x;
    if (e < E) atomicAdd(&cnt[dst[e]], 1);
}

__global__ void scan_reduce(const int* __restrict__ cnt, int* __restrict__ csum, int n) {
    __shared__ int s[256];
    int base = blockIdx.x * SCAN_CHUNK;
    int v = 0;
    for (int i = threadIdx.x; i < SCAN_CHUNK; i += 256) {
        int idx = base + i;
        v += (idx < n) ? cnt[idx] : 0;
    }
    s[threadIdx.x] = v; __syncthreads();
    for (int o = 128; o > 0; o >>= 1) {
        if (threadIdx.x < o) s[threadIdx.x] += s[threadIdx.x + o];
        __syncthreads();
    }
    if (threadIdx.x == 0) csum[blockIdx.x] = s[0];
}

__global__ void scan_sums(const int* __restrict__ csum, int* __restrict__ coff, int nchunks) {
    __shared__ int s[1024];
    int t = threadIdx.x;
    s[t] = (t < nchunks) ? csum[t] : 0;
    __syncthreads();
    for (int o = 1; o < 1024; o <<= 1) {
        int v = (t >= o) ? s[t - o] : 0;
        __syncthreads();
        s[t] += v;
        __syncthreads();
    }
    if (t < nchunks) coff[t] = (t == 0) ? 0 : s[t - 1];
}

__global__ void scan_apply(const int* __restrict__ cnt, const int* __restrict__ coff,
                           int* __restrict__ off, int* __restrict__ cursor, int n) {
    __shared__ int s[256];
    int b = blockIdx.x, t = threadIdx.x;
    if (b == 0 && t == 0) off[0] = 0;
    int base = b * SCAN_CHUNK + t * 4;
    int v[4];
    #pragma unroll
    for (int i = 0; i < 4; ++i) v[i] = (base + i < n) ? cnt[base + i] : 0;
    s[t] = v[0] + v[1] + v[2] + v[3];
    __syncthreads();
    for (int o = 1; o < 256; o <<= 1) {
        int x = (t >= o) ? s[t - o] : 0;
        __syncthreads();
        s[t] += x;
        __syncthreads();
    }
    int run = coff[b] + ((t > 0) ? s[t - 1] : 0);
    #pragma unroll
    for (int i = 0; i < 4; ++i) {
        if (base + i < n) cursor[base + i] = run;   // bucket start
        run += v[i];
        if (base + i < n) off[base + i + 1] = run;
    }
}

__global__ void fill_elist(const int* __restrict__ dst, int* __restrict__ cursor,
                           int* __restrict__ elist, int E) {
    int e = blockIdx.x * 256 + threadIdx.x;
    if (e < E) {
        int p = atomicAdd(&cursor[dst[e]], 1);
        elist[p] = e;
    }
}

__global__ void sort_buckets(const int* __restrict__ off, int* __restrict__ elist, int N) {
    int n = blockIdx.x * 256 + threadIdx.x;
    if (n >= N) return;
    int s = off[n], t = off[n + 1];
    for (int i = s; i < t - 1; ++i) {
        int mn = elist[i], mi = i;
        for (int j = i + 1; j < t; ++j) {
            int v = elist[j];
            if (v < mn) { mn = v; mi = j; }
        }
        if (mi != i) { elist[mi] = elist[i]; elist[i] = mn; }
    }
}

// ====== gather: M[n] = sum_{f in in(n)} w[f]*h[f] -> bf16, batched loads ======
__global__ void gather_M(const unsigned short* __restrict__ h, const float* __restrict__ w,
                         const int* __restrict__ off, const int* __restrict__ elist,
                         unsigned short* __restrict__ Mb, int N) {
    int n = blockIdx.x * 4 + (threadIdx.x >> 6);
    if (n >= N) return;
    int c = (threadIdx.x & 63) * 4;
    int s = off[n], e_ = off[n + 1];
    float4 acc = {0.f, 0.f, 0.f, 0.f};
    for (int i = s; i < e_; i += 4) {
        int m = e_ - i;
        int f[4]; float wf[4]; u16x4 hv[4];
        #pragma unroll
        for (int j = 0; j < 4; ++j) if (j < m) f[j] = elist[i + j];
        #pragma unroll
        for (int j = 0; j < 4; ++j) if (j < m) {
            wf[j] = w[f[j]];
            hv[j] = *(const u16x4*)&h[(size_t)f[j] * HDIM + c];
        }
        #pragma unroll
        for (int j = 0; j < 4; ++j) if (j < m) {
            acc.x += wf[j] * bf2f(hv[j][0]);
            acc.y += wf[j] * bf2f(hv[j][1]);
            acc.z += wf[j] * bf2f(hv[j][2]);
            acc.w += wf[j] * bf2f(hv[j][3]);
        }
    }
    u16x4 o;
    o[0] = f2bf(acc.x); o[1] = f2bf(acc.y); o[2] = f2bf(acc.z); o[3] = f2bf(acc.w);
    *(u16x4*)&Mb[(size_t)n * HDIM + c] = o;
}

// ============ graph_embeds[g] = sum over node range (n2g sorted) ============
__global__ void graph_sum(const float* __restrict__ nr, const int* __restrict__ n2g,
                          float* __restrict__ ge, int N) {
    int g = blockIdx.x, t = threadIdx.x;
    int lo = 0, hi = N;
    while (lo < hi) { int mid = (lo + hi) >> 1; if (n2g[mid] < g) lo = mid + 1; else hi = mid; }
    int start = lo;
    hi = N;
    while (lo < hi) { int mid = (lo + hi) >> 1; if (n2g[mid] < g + 1) lo = mid + 1; else hi = mid; }
    int end = lo;
    float acc = 0.0f;
    for (int n = start; n < end; ++n) acc += nr[(size_t)n * HDIM + t];
    ge[(size_t)g * HDIM + t] = acc;
}

// ============ fused graph head: pred[g] = relu(ge[g]@gh0^T + b0) . gh2 + b2 ============
__global__ __launch_bounds__(256) void graph_head(
    const float* __restrict__ ge,              // [G][256]
    const float* __restrict__ w0, const float* __restrict__ b0,
    const float* __restrict__ w2, const float* __restrict__ b2,
    float* __restrict__ pred, int G)
{
    int g = blockIdx.x;
    if (g >= G) return;
    __shared__ float xs[256];
    __shared__ float ys[256];
    int t = threadIdx.x;
    xs[t] = ge[(size_t)g * 256 + t];
    __syncthreads();
    float acc = b0[t];
    const float* wr = w0 + (size_t)t * 256;
    #pragma unroll 8
    for (int k = 0; k < 256; ++k) acc = fmaf(wr[k], xs[k], acc);
    ys[t] = fmaxf(acc, 0.0f) * w2[t];
    __syncthreads();
    for (int o = 128; o > 0; o >>= 1) {
        if (t < o) ys[t] += ys[t + o];
        __syncthreads();
    }
    if (t == 0) pred[g] = ys[0] + b2[0];
}

extern "C" void kernel_launch(void* const* d_in, const int* in_sizes, int n_in,
                              void* d_out, int out_size, void* d_ws, size_t ws_size,
                              hipStream_t stream) {
    const float* atom_feats   = (const float*)d_in[0];
    const float* edge_feats   = (const float*)d_in[1];
    const float* edge_weights = (const float*)d_in[2];
    const float* Wi    = (const float*)d_in[3];
    const float* Wm_w  = (const float*)d_in[4];
    const float* Wm_b  = (const float*)d_in[5];
    const float* Wn_w  = (const float*)d_in[6];
    const float* Wn_b  = (const float*)d_in[7];
    const float* nh0_w = (const float*)d_in[8];
    const float* nh0_b = (const float*)d_in[9];
    const float* nh2_w = (const float*)d_in[10];
    const float* nh2_b = (const float*)d_in[11];
    const float* eh0_w = (const float*)d_in[12];
    const float* eh0_b = (const float*)d_in[13];
    const float* eh2_w = (const float*)d_in[14];
    const float* eh2_b = (const float*)d_in[15];
    const float* gh0_w = (const float*)d_in[16];
    const float* gh0_b = (const float*)d_in[17];
    const float* gh2_w = (const float*)d_in[18];
    const float* gh2_b = (const float*)d_in[19];
    const int* edge_src      = (const int*)d_in[20];
    const int* edge_dst      = (const int*)d_in[21];
    // d_in[22]=b2rev: always e^1 and valid; unused.
    const int* node_to_graph = (const int*)d_in[23];

    int N = in_sizes[0] / ATOMF;
    int E = in_sizes[1] / BONDF;
    long long G = ((long long)out_size - (long long)N * (ATOMF + HDIM)
                   - (long long)E * (BONDF + HDIM)) / (1 + HDIM);

    // d_out slices
    float* out = (float*)d_out;
    float* pred_node = out;
    float* pred_edge = pred_node + (size_t)N * ATOMF;
    float* pred_grph = pred_edge + (size_t)E * BONDF;
    float* gemb      = pred_grph + (size_t)G;
    float* node_repr = gemb + (size_t)G * HDIM;
    float* h_f32     = node_repr + (size_t)N * HDIM;

    // workspace layout (single h buffer: in-place update keeps loop working set ~L3-sized)
    unsigned short* hA    = (unsigned short*)d_ws;      // E*256
    unsigned short* nrb   = hA + (size_t)E * HDIM;      // N*256 (node_repr bf16)
    unsigned short* Mb    = nrb + (size_t)N * HDIM;     // N*256
    unsigned short* atomb = Mb + (size_t)N * HDIM;      // N*160
    unsigned short* Wib   = atomb + (size_t)N * 160;
    unsigned short* Wmb   = Wib + 256 * 160;
    unsigned short* Wnb   = Wmb + 256 * 256;
    unsigned short* nh0b  = Wnb + 256 * KWN;
    unsigned short* nh2b  = nh0b + 256 * 256;
    unsigned short* eh0b  = nh2b + 256 * 256;
    unsigned short* eh2b  = eh0b + 256 * 256;
    int* csr = (int*)(eh2b + 256 * 256);
    int* cnt    = csr;
    int* off    = cnt + N;
    int* cursor = off + N + 1;
    int* elist  = cursor + N;
    int* csum   = elist + E;
    int* coff   = csum + 1024;

    int nchunks = (N + SCAN_CHUNK - 1) / SCAN_CHUNK;

    // ---- CSR build (per launch; deterministic via sort) ----
    hipMemsetAsync(cnt, 0, (size_t)N * sizeof(int), stream);
    count_dst<<<(E + 255) / 256, 256, 0, stream>>>(edge_dst, cnt, E);
    scan_reduce<<<nchunks, 256, 0, stream>>>(cnt, csum, N);
    scan_sums<<<1, 1024, 0, stream>>>(csum, coff, nchunks);
    scan_apply<<<nchunks, 256, 0, stream>>>(cnt, coff, off, cursor, N);
    fill_elist<<<(E + 255) / 256, 256, 0, stream>>>(edge_dst, cursor, elist, E);
    sort_buckets<<<(N + 255) / 256, 256, 0, stream>>>(off, elist, N);

    // ---- weight conversion + atom pre-convert ----
    pad_all<<<7 * 256, 256, 0, stream>>>(Wi, Wm_w, Wn_w, nh0_w, nh2_w, eh0_w, eh2_w,
                                         Wib, Wmb, Wnb, nh0b, nh2b, eh0b, eh2b);
    atom_conv<<<(N + 3) / 4, 640, 0, stream>>>(atom_feats, atomb, N);

    // ---- 1) h0 = relu([atom[src], bond] @ Wi^T) -> hA ----
    mfma_gemm_cat<<<(E + 127) / 128, 512, 0, stream>>>(atomb, edge_feats, edge_src,
                                                       E, Wib, hA);

    // ---- 2) message-passing loop: gather_M + fused msg-GEMM, h updated IN PLACE ----
    int ngrid = (N + 3) / 4;
    for (int d = 0; d < DEPTH_HC; ++d) {
        gather_M<<<ngrid, 256, 0, stream>>>(hA, edge_weights, off, elist, Mb, N);
        float* cf = (d == DEPTH_HC - 1) ? h_f32 : nullptr;
        mfma_gemm_msg<<<(E + 127) / 128, 512, 0, stream>>>(
            Mb, hA, edge_weights, edge_src, E, Wmb, Wm_b, cf);
    }

    // ---- 3) edge head: fused 2-layer, writes pred_edge directly ----
    head_fused<<<(E + 127) / 128, 512, 0, stream>>>(hA, E, eh0b, eh0_b, eh2b, eh2_b,
                                                    pred_edge, BONDF);

    // ---- 4) node_agg (gather) + fused cat+Wn GEMM -> node_repr (f32 + bf16 into nrb) ----
    gather_M<<<ngrid, 256, 0, stream>>>(hA, edge_weights, off, elist, Mb, N);
    mfma_gemm_catwn<<<(N + 127) / 128, 512, 0, stream>>>(atomb, Mb, N, Wnb, Wn_b,
                                                         node_repr, nrb);

    // ---- 5) graph embeds ----
    graph_sum<<<(int)G, HDIM, 0, stream>>>(node_repr, node_to_graph, gemb, N);

    // ---- 6) node head: fused 2-layer, writes pred_node directly ----
    head_fused<<<(N + 127) / 128, 512, 0, stream>>>(nrb, N, nh0b, nh0_b, nh2b, nh2_b,
                                                    pred_node, ATOMF);

    // ---- 7) graph head (fused 2-layer, one dispatch) ----
    graph_head<<<(int)G, 256, 0, stream>>>(gemb, gh0_w, gh0_b, gh2_w, gh2_b,
                                           pred_grph, (int)G);
}

// Round 13
// 1759.864 us; speedup vs baseline: 1.0862x; 1.0862x over previous
//
#include <hip/hip_runtime.h>
#include <hip/hip_bf16.h>

#define HDIM 256
#define ATOMF 133
#define BONDF 14
#define DEPTH_HC 4
#define SCAN_CHUNK 1024
#define KWN 416   // Wn GEMM K: atomb [0,160), M [160,416)

typedef short bf16x8 __attribute__((ext_vector_type(8)));
typedef float f32x4 __attribute__((ext_vector_type(4)));
typedef unsigned short u16x8 __attribute__((ext_vector_type(8)));
typedef unsigned short u16x4 __attribute__((ext_vector_type(4)));

__device__ inline float bf2f(unsigned short u) {
    unsigned int x = ((unsigned int)u) << 16;
    float f; __builtin_memcpy(&f, &x, 4); return f;
}
__device__ inline unsigned short f2bf(float f) {
    __hip_bfloat16 h = __float2bfloat16(f);
    unsigned short u; __builtin_memcpy(&u, &h, 2); return u;
}

__device__ inline void gload_lds16(const unsigned short* g, unsigned short* lds) {
    __builtin_amdgcn_global_load_lds(
        (const __attribute__((address_space(1))) unsigned int*)g,
        (__attribute__((address_space(3))) unsigned int*)lds, 16, 0, 0);
}

// common MFMA step: compute 4x4 accumulators from As/Bs buffers
#define MFMA_STEP(ASB, BSB)                                                        \
    {                                                                              \
        const int kq = (l >> 4) * 8;                                               \
        const int rbase = (wr << 6) + (l & 15);                                    \
        const int cbase = (wc << 6) + (l & 15);                                    \
        bf16x8 af[4], bfr[4];                                                      \
        _Pragma("unroll")                                                          \
        for (int i = 0; i < 4; ++i) {                                              \
            af[i]  = *(const bf16x8*)&(ASB)[(rbase + i * 16) * 32 + kq];           \
            bfr[i] = *(const bf16x8*)&(BSB)[(cbase + i * 16) * 32 + kq];           \
        }                                                                          \
        _Pragma("unroll")                                                          \
        for (int mi = 0; mi < 4; ++mi)                                             \
            _Pragma("unroll")                                                      \
            for (int ni = 0; ni < 4; ++ni)                                         \
                acc[mi][ni] = __builtin_amdgcn_mfma_f32_16x16x32_bf16(             \
                    af[mi], bfr[ni], acc[mi][ni], 0, 0, 0);                        \
    }

// ========== fused cat+GEMM1: h0 = relu([atomb[src[e]]|bond-overlay] @ Wi^T), K=160 ==========
__global__ __launch_bounds__(512) void mfma_gemm_cat(
    const unsigned short* __restrict__ atomb,  // [N][160] bf16, zero-padded
    const float* __restrict__ bond,
    const int* __restrict__ src, int E,
    const unsigned short* __restrict__ W,      // Wib [256][160] bf16
    unsigned short* __restrict__ Cb)           // h [E][256]
{
    __shared__ unsigned short As[2][128 * 32];
    __shared__ unsigned short Bs[2][256 * 32];
    const int t = threadIdx.x;
    const int w = t >> 6, l = t & 63;
    const int m0 = blockIdx.x * 128;
    const int wr = w >> 2, wc = w & 3;

    f32x4 acc[4][4] = {};

    const int ar = t >> 2;
    const int ac0 = (t & 3) * 8;
    long long e_row = m0 + ar; if (e_row > E - 1) e_row = E - 1;
    const int sn = src[e_row];
    const unsigned short* arow = atomb + (size_t)sn * 160;
    const float* brow = bond + (size_t)e_row * BONDF;

    // tail chunk (chunk 4, cols 128..159): atom[128,133) | bond | zeros
    u16x8 tail = *(const u16x8*)&arow[128 + ac0];
    #pragma unroll
    for (int i = 0; i < 8; ++i) {
        int k = 128 + ac0 + i;
        if (k >= ATOMF && k < ATOMF + BONDF) tail[i] = f2bf(brow[k - ATOMF]);
    }

    const int kcol = (l & 3) * 8;
    const int rowL = (w << 4) + (l >> 2);

    {
        u16x8 o = *(const u16x8*)&arow[ac0];
        *(u16x8*)&As[0][ar * 32 + ac0] = o;
        gload_lds16(W + (size_t)rowL * 160 + kcol, Bs[0] + (size_t)w * 512);
        gload_lds16(W + (size_t)(128 + rowL) * 160 + kcol, Bs[0] + 4096 + (size_t)w * 512);
    }
    u16x8 regs = *(const u16x8*)&arow[32 + ac0];   // chunk 1
    __syncthreads();

    #pragma unroll
    for (int c = 0; c < 5; ++c) {      // k0 = c*32, K=160
        const int cb = c & 1, nb = cb ^ 1;
        if (c + 1 < 5) {
            u16x8 o = (c + 1 == 4) ? tail : regs;
            *(u16x8*)&As[nb][ar * 32 + ac0] = o;
            gload_lds16(W + (size_t)rowL * 160 + (c + 1) * 32 + kcol, Bs[nb] + (size_t)w * 512);
            gload_lds16(W + (size_t)(128 + rowL) * 160 + (c + 1) * 32 + kcol,
                        Bs[nb] + 4096 + (size_t)w * 512);
            if (c + 2 < 4) regs = *(const u16x8*)&arow[(c + 2) * 32 + ac0];
        }
        MFMA_STEP(As[cb], Bs[cb]);
        __syncthreads();
    }

    const int ccol = l & 15, crow = (l >> 4) * 4;
    #pragma unroll
    for (int ni = 0; ni < 4; ++ni) {
        int gn = (wc << 6) + ni * 16 + ccol;
        #pragma unroll
        for (int mi = 0; mi < 4; ++mi) {
            #pragma unroll
            for (int j = 0; j < 4; ++j) {
                long long gm = m0 + (wr << 6) + mi * 16 + crow + j;
                if (gm >= E) continue;
                float v = fmaxf(acc[mi][ni][j], 0.0f);
                Cb[(size_t)gm * HDIM + gn] = f2bf(v);
            }
        }
    }
}

// ========== fused msg+GEMM, IN-PLACE (round-11 proven 2-phase schedule) ==========
// h[e] <- relu((M[src[e]] - w[e^1]h[e^1]) @ Wm^T + b); h_f32 (last iter) via nt-stores.
__global__ __launch_bounds__(512) void mfma_gemm_msg(
    const unsigned short* __restrict__ Mb,  // [N][256] bf16
    unsigned short* h,                      // [E][256] bf16, read+written in place
    const float* __restrict__ w,
    const int* __restrict__ src, int E,
    const unsigned short* __restrict__ W,   // Wmb [256][256] bf16
    const float* __restrict__ bias,         // Wm_b
    float* __restrict__ Cf)                 // h_f32 (last iter) or null
{
    __shared__ unsigned short As[2][128 * 32];
    __shared__ unsigned short Bs[2][256 * 32];
    const int t = threadIdx.x;
    const int wv = t >> 6, l = t & 63;
    const int m0 = blockIdx.x * 128;
    const int wr = wv >> 2, wc = wv & 3;

    f32x4 acc[4][4] = {};

    const int ar = t >> 2;
    const int ac0 = (t & 3) * 8;
    long long e_row = m0 + ar; if (e_row > E - 1) e_row = E - 1;
    const long long er1 = e_row ^ 1;
    const int sn = src[e_row];
    const float we1 = w[er1];
    const unsigned short* mrow = Mb + (size_t)sn * HDIM;
    const unsigned short* hrow = h + (size_t)er1 * HDIM;

    const int kcol = (l & 3) * 8;
    const int rowL = (wv << 4) + (l >> 2);

    {
        u16x8 Mv = *(const u16x8*)&mrow[ac0];
        u16x8 hv = *(const u16x8*)&hrow[ac0];
        u16x8 o;
        #pragma unroll
        for (int i = 0; i < 8; ++i) o[i] = f2bf(bf2f(Mv[i]) - we1 * bf2f(hv[i]));
        *(u16x8*)&As[0][ar * 32 + ac0] = o;
        gload_lds16(W + (size_t)rowL * 256 + kcol, Bs[0] + (size_t)wv * 512);
        gload_lds16(W + (size_t)(128 + rowL) * 256 + kcol, Bs[0] + 4096 + (size_t)wv * 512);
    }
    u16x8 Mr = *(const u16x8*)&mrow[32 + ac0];
    u16x8 hr = *(const u16x8*)&hrow[32 + ac0];
    __syncthreads();

    #pragma unroll
    for (int c = 0; c < 8; ++c) {      // k0 = c*32, K=256
        const int cb = c & 1, nb = cb ^ 1;
        if (c + 1 < 8) {
            u16x8 o;
            #pragma unroll
            for (int i = 0; i < 8; ++i) o[i] = f2bf(bf2f(Mr[i]) - we1 * bf2f(hr[i]));
            *(u16x8*)&As[nb][ar * 32 + ac0] = o;
            gload_lds16(W + (size_t)rowL * 256 + (c + 1) * 32 + kcol, Bs[nb] + (size_t)wv * 512);
            gload_lds16(W + (size_t)(128 + rowL) * 256 + (c + 1) * 32 + kcol,
                        Bs[nb] + 4096 + (size_t)wv * 512);
            if (c + 2 < 8) {
                Mr = *(const u16x8*)&mrow[(c + 2) * 32 + ac0];
                hr = *(const u16x8*)&hrow[(c + 2) * 32 + ac0];
            }
        }
        MFMA_STEP(As[cb], Bs[cb]);
        __syncthreads();
    }
    // all reads of h rows in this tile are complete (barrier above) -> in-place write safe

    const int ccol = l & 15, crow = (l >> 4) * 4;
    #pragma unroll
    for (int ni = 0; ni < 4; ++ni) {
        int gn = (wc << 6) + ni * 16 + ccol;
        float bv = bias[gn];
        #pragma unroll
        for (int mi = 0; mi < 4; ++mi) {
            #pragma unroll
            for (int j = 0; j < 4; ++j) {
                long long gm = m0 + (wr << 6) + mi * 16 + crow + j;
                if (gm >= E) continue;
                float v = fmaxf(acc[mi][ni][j] + bv, 0.0f);
                if (Cf) __builtin_nontemporal_store(v, &Cf[(size_t)gm * HDIM + gn]);
                h[(size_t)gm * HDIM + gn] = f2bf(v);
            }
        }
    }
}

// ========== fused cat+Wn GEMM: node_repr = relu([atomb[n]|Mb[n]] @ Wnb^T + b), K=416 ==========
__global__ __launch_bounds__(512) void mfma_gemm_catwn(
    const unsigned short* __restrict__ atomb,  // [N][160] bf16 zero-padded
    const unsigned short* __restrict__ Mb,     // [N][256] bf16
    int N,
    const unsigned short* __restrict__ W,      // Wnb [256][416] bf16
    const float* __restrict__ bias,            // Wn_b
    float* __restrict__ Cf,                    // node_repr f32 [N][256] (nt-stored)
    unsigned short* __restrict__ Cb)           // node_repr bf16 [N][256]
{
    __shared__ unsigned short As[2][128 * 32];
    __shared__ unsigned short Bs[2][256 * 32];
    const int t = threadIdx.x;
    const int wv = t >> 6, l = t & 63;
    const int m0 = blockIdx.x * 128;
    const int wr = wv >> 2, wc = wv & 3;

    f32x4 acc[4][4] = {};

    const int ar = t >> 2;
    const int ac0 = (t & 3) * 8;
    long long nrow = m0 + ar; if (nrow > N - 1) nrow = N - 1;
    const unsigned short* arow = atomb + (size_t)nrow * 160;
    const unsigned short* mrow = Mb + (size_t)nrow * HDIM;

    const int kcol = (l & 3) * 8;
    const int rowL = (wv << 4) + (l >> 2);

    #define LOADA_WN(c) ((c) < 5 ? *(const u16x8*)&arow[(c) * 32 + ac0] \
                                 : *(const u16x8*)&mrow[(c) * 32 - 160 + ac0])

    {
        u16x8 o = LOADA_WN(0);
        *(u16x8*)&As[0][ar * 32 + ac0] = o;
        gload_lds16(W + (size_t)rowL * KWN + kcol, Bs[0] + (size_t)wv * 512);
        gload_lds16(W + (size_t)(128 + rowL) * KWN + kcol, Bs[0] + 4096 + (size_t)wv * 512);
    }
    u16x8 regs = LOADA_WN(1);
    __syncthreads();

    #pragma unroll
    for (int c = 0; c < 13; ++c) {     // k0 = c*32, K=416
        const int cb = c & 1, nb = cb ^ 1;
        if (c + 1 < 13) {
            *(u16x8*)&As[nb][ar * 32 + ac0] = regs;
            gload_lds16(W + (size_t)rowL * KWN + (c + 1) * 32 + kcol, Bs[nb] + (size_t)wv * 512);
            gload_lds16(W + (size_t)(128 + rowL) * KWN + (c + 1) * 32 + kcol,
                        Bs[nb] + 4096 + (size_t)wv * 512);
            if (c + 2 < 13) regs = LOADA_WN(c + 2);
        }
        MFMA_STEP(As[cb], Bs[cb]);
        __syncthreads();
    }
    #undef LOADA_WN

    const int ccol = l & 15, crow = (l >> 4) * 4;
    #pragma unroll
    for (int ni = 0; ni < 4; ++ni) {
        int gn = (wc << 6) + ni * 16 + ccol;
        float bv = bias[gn];
        #pragma unroll
        for (int mi = 0; mi < 4; ++mi) {
            #pragma unroll
            for (int j = 0; j < 4; ++j) {
                long long gm = m0 + (wr << 6) + mi * 16 + crow + j;
                if (gm >= N) continue;
                float v = fmaxf(acc[mi][ni][j] + bv, 0.0f);
                __builtin_nontemporal_store(v, &Cf[(size_t)gm * HDIM + gn]);
                Cb[(size_t)gm * HDIM + gn] = f2bf(v);
            }
        }
    }
}

// ========== fused 2-layer head: pred = relu(A@W^T + b0) @ W2^T + b2 (K=256, NOUT2<=144) ==========
__global__ __launch_bounds__(512) void head_fused(
    const unsigned short* __restrict__ A, int Mrows,
    const unsigned short* __restrict__ W,       // [256][256] bf16
    const float* __restrict__ b0,               // [256]
    const unsigned short* __restrict__ W2b,     // [256][256] bf16 (rows = out cols, padded 0)
    const float* __restrict__ b2,               // [NOUT2]
    float* __restrict__ pred, int NOUT2)        // [M][NOUT2] (nt-stored)
{
    __shared__ unsigned short R[128 * 256];     // 64KB
    unsigned short* As0 = R;
    unsigned short* As1 = R + 4096;
    unsigned short* Bs0 = R + 8192;
    unsigned short* Bs1 = R + 16384;
    unsigned short* AsB[2] = {As0, As1};
    unsigned short* BsB[2] = {Bs0, Bs1};
    const int t = threadIdx.x;
    const int w = t >> 6, l = t & 63;
    const int m0 = blockIdx.x * 128;
    const int wr = w >> 2, wc = w & 3;
    const int kq = (l >> 4) * 8;

    f32x4 acc[4][4] = {};
    const int kcol = (l & 3) * 8;
    const int rowL = (w << 4) + (l >> 2);
    long long r0 = m0 + rowL; if (r0 > Mrows - 1) r0 = Mrows - 1;

    {
        gload_lds16(A + (size_t)r0 * 256 + kcol, As0 + (size_t)w * 512);
        gload_lds16(W + (size_t)rowL * 256 + kcol, Bs0 + (size_t)w * 512);
        gload_lds16(W + (size_t)(128 + rowL) * 256 + kcol, Bs0 + 4096 + (size_t)w * 512);
    }
    __syncthreads();

    #pragma unroll
    for (int c = 0; c < 8; ++c) {
        const int cb = c & 1, nb = cb ^ 1;
        if (c + 1 < 8) {
            gload_lds16(A + (size_t)r0 * 256 + (c + 1) * 32 + kcol, AsB[nb] + (size_t)w * 512);
            gload_lds16(W + (size_t)rowL * 256 + (c + 1) * 32 + kcol, BsB[nb] + (size_t)w * 512);
            gload_lds16(W + (size_t)(128 + rowL) * 256 + (c + 1) * 32 + kcol,
                        BsB[nb] + 4096 + (size_t)w * 512);
        }
        MFMA_STEP(AsB[cb], BsB[cb]);
        __syncthreads();
    }

    // phase 1: write relu(acc + b0) -> R, XOR-swizzled
    const int ccol = l & 15, crow = (l >> 4) * 4;
    #pragma unroll
    for (int ni = 0; ni < 4; ++ni) {
        const int col = (wc << 6) + ni * 16 + ccol;
        const float bv = b0[col];
        #pragma unroll
        for (int mi = 0; mi < 4; ++mi) {
            #pragma unroll
            for (int j = 0; j < 4; ++j) {
                const int rr = (wr << 6) + mi * 16 + crow + j;
                float v = fmaxf(acc[mi][ni][j] + bv, 0.0f);
                size_t byteoff = ((size_t)rr * 512 + (size_t)col * 2) ^ (size_t)((rr & 7) << 4);
                *(unsigned short*)((char*)R + byteoff) = f2bf(v);
            }
        }
    }
    __syncthreads();

    // phase 2: wave w -> e-rows w*16..+15; loop over 16-col output groups
    const int erow = (w << 4) + (l & 15);
    const int jrow = l & 15;
    for (int cc = 0; cc * 16 < NOUT2; ++cc) {
        bf16x8 w2b[8];
        #pragma unroll
        for (int ks = 0; ks < 8; ++ks)
            w2b[ks] = *(const bf16x8*)&W2b[(size_t)(cc * 16 + jrow) * 256 + ks * 32 + kq];
        f32x4 acc2 = {};
        #pragma unroll
        for (int ks = 0; ks < 8; ++ks) {
            size_t byteoff = ((size_t)erow * 512 + (size_t)(ks * 64 + kq * 2))
                             ^ (size_t)((erow & 7) << 4);
            bf16x8 af;
            __builtin_memcpy(&af, (char*)R + byteoff, 16);
            acc2 = __builtin_amdgcn_mfma_f32_16x16x32_bf16(af, w2b[ks], acc2, 0, 0, 0);
        }
        const int col = cc * 16 + jrow;
        if (col < NOUT2) {
            #pragma unroll
            for (int j = 0; j < 4; ++j) {
                long long gm = m0 + (w << 4) + (l >> 4) * 4 + j;
                if (gm < Mrows)
                    __builtin_nontemporal_store(acc2[j] + b2[col], &pred[gm * NOUT2 + col]);
            }
        }
    }
}

// ============ atom f32 [N][133] -> bf16 [N][160] zero-padded ============
__global__ __launch_bounds__(640) void atom_conv(const float* __restrict__ a,
                                                 unsigned short* __restrict__ ab, int N) {
    int n = blockIdx.x * 4 + threadIdx.x / 160;
    int c = threadIdx.x % 160;
    if (n >= N) return;
    ab[(size_t)n * 160 + c] = (c < ATOMF) ? f2bf(a[(size_t)n * ATOMF + c]) : (unsigned short)0;
}

// ============ all weight pads in one kernel (7 weights) ============
__global__ void pad_all(const float* Wi, const float* Wm, const float* Wn,
                        const float* n0, const float* n2, const float* e0, const float* e2,
                        unsigned short* Wib, unsigned short* Wmb, unsigned short* Wnb,
                        unsigned short* n0b, unsigned short* n2b, unsigned short* e0b,
                        unsigned short* e2b) {
    int wid = blockIdx.x >> 8;
    int r = blockIdx.x & 255;
    if (wid == 2) {  // Wn [256][389] -> [256][416]: atom cols [0,133), M cols [160,416)
        for (int c = threadIdx.x; c < KWN; c += blockDim.x) {
            float v = 0.0f;
            if (c < ATOMF)      v = Wn[(size_t)r * 389 + c];
            else if (c >= 160)  v = Wn[(size_t)r * 389 + (c - 27)];
            Wnb[(size_t)r * KWN + c] = f2bf(v);
        }
        return;
    }
    const float* S; unsigned short* D; int R, C, Cp;
    switch (wid) {
        case 0: S = Wi; D = Wib; R = 256; C = 147; Cp = 160; break;
        case 1: S = Wm; D = Wmb; R = 256; C = 256; Cp = 256; break;
        case 3: S = n0; D = n0b; R = 256; C = 256; Cp = 256; break;
        case 4: S = n2; D = n2b; R = 133; C = 256; Cp = 256; break;
        case 5: S = e0; D = e0b; R = 256; C = 256; Cp = 256; break;
        default: S = e2; D = e2b; R = 14;  C = 256; Cp = 256; break;
    }
    for (int c = threadIdx.x; c < Cp; c += blockDim.x) {
        float v = (r < R && c < C) ? S[(size_t)r * C + c] : 0.0f;
        D[(size_t)r * Cp + c] = f2bf(v);
    }
}

// ================== CSR build ==================
__global__ void count_dst(const int* __restrict__ dst, int* __restrict__ cnt, int E) {
    int e = blockIdx.x * 256 + threadIdx.x;
    if (e < E) atomicAdd(&cnt[dst[e]], 1);
}

__global__ void scan_reduce(const int* __restrict__ cnt, int* __restrict__ csum, int n) {
    __shared__ int s[256];
    int base = blockIdx.x * SCAN_CHUNK;
    int v = 0;
    for (int i = threadIdx.x; i < SCAN_CHUNK; i += 256) {
        int idx = base + i;
        v += (idx < n) ? cnt[idx] : 0;
    }
    s[threadIdx.x] = v; __syncthreads();
    for (int o = 128; o > 0; o >>= 1) {
        if (threadIdx.x < o) s[threadIdx.x] += s[threadIdx.x + o];
        __syncthreads();
    }
    if (threadIdx.x == 0) csum[blockIdx.x] = s[0];
}

__global__ void scan_sums(const int* __restrict__ csum, int* __restrict__ coff, int nchunks) {
    __shared__ int s[1024];
    int t = threadIdx.x;
    s[t] = (t < nchunks) ? csum[t] : 0;
    __syncthreads();
    for (int o = 1; o < 1024; o <<= 1) {
        int v = (t >= o) ? s[t - o] : 0;
        __syncthreads();
        s[t] += v;
        __syncthreads();
    }
    if (t < nchunks) coff[t] = (t == 0) ? 0 : s[t - 1];
}

__global__ void scan_apply(const int* __restrict__ cnt, const int* __restrict__ coff,
                           int* __restrict__ off, int* __restrict__ cursor, int n) {
    __shared__ int s[256];
    int b = blockIdx.x, t = threadIdx.x;
    if (b == 0 && t == 0) off[0] = 0;
    int base = b * SCAN_CHUNK + t * 4;
    int v[4];
    #pragma unroll
    for (int i = 0; i < 4; ++i) v[i] = (base + i < n) ? cnt[base + i] : 0;
    s[t] = v[0] + v[1] + v[2] + v[3];
    __syncthreads();
    for (int o = 1; o < 256; o <<= 1) {
        int x = (t >= o) ? s[t - o] : 0;
        __syncthreads();
        s[t] += x;
        __syncthreads();
    }
    int run = coff[b] + ((t > 0) ? s[t - 1] : 0);
    #pragma unroll
    for (int i = 0; i < 4; ++i) {
        if (base + i < n) cursor[base + i] = run;   // bucket start
        run += v[i];
        if (base + i < n) off[base + i + 1] = run;
    }
}

__global__ void fill_elist(const int* __restrict__ dst, int* __restrict__ cursor,
                           int* __restrict__ elist, int E) {
    int e = blockIdx.x * 256 + threadIdx.x;
    if (e < E) {
        int p = atomicAdd(&cursor[dst[e]], 1);
        elist[p] = e;
    }
}

__global__ void sort_buckets(const int* __restrict__ off, int* __restrict__ elist, int N) {
    int n = blockIdx.x * 256 + threadIdx.x;
    if (n >= N) return;
    int s = off[n], t = off[n + 1];
    for (int i = s; i < t - 1; ++i) {
        int mn = elist[i], mi = i;
        for (int j = i + 1; j < t; ++j) {
            int v = elist[j];
            if (v < mn) { mn = v; mi = j; }
        }
        if (mi != i) { elist[mi] = elist[i]; elist[i] = mn; }
    }
}

// ====== gather: M[n] = sum_{f in in(n)} w[f]*h[f] -> bf16, batched loads ======
__global__ void gather_M(const unsigned short* __restrict__ h, const float* __restrict__ w,
                         const int* __restrict__ off, const int* __restrict__ elist,
                         unsigned short* __restrict__ Mb, int N) {
    int n = blockIdx.x * 4 + (threadIdx.x >> 6);
    if (n >= N) return;
    int c = (threadIdx.x & 63) * 4;
    int s = off[n], e_ = off[n + 1];
    float4 acc = {0.f, 0.f, 0.f, 0.f};
    for (int i = s; i < e_; i += 4) {
        int m = e_ - i;
        int f[4]; float wf[4]; u16x4 hv[4];
        #pragma unroll
        for (int j = 0; j < 4; ++j) if (j < m) f[j] = elist[i + j];
        #pragma unroll
        for (int j = 0; j < 4; ++j) if (j < m) {
            wf[j] = w[f[j]];
            hv[j] = *(const u16x4*)&h[(size_t)f[j] * HDIM + c];
        }
        #pragma unroll
        for (int j = 0; j < 4; ++j) if (j < m) {
            acc.x += wf[j] * bf2f(hv[j][0]);
            acc.y += wf[j] * bf2f(hv[j][1]);
            acc.z += wf[j] * bf2f(hv[j][2]);
            acc.w += wf[j] * bf2f(hv[j][3]);
        }
    }
    u16x4 o;
    o[0] = f2bf(acc.x); o[1] = f2bf(acc.y); o[2] = f2bf(acc.z); o[3] = f2bf(acc.w);
    *(u16x4*)&Mb[(size_t)n * HDIM + c] = o;
}

// ============ graph_embeds[g] = sum over node range (n2g sorted) ============
__global__ void graph_sum(const float* __restrict__ nr, const int* __restrict__ n2g,
                          float* __restrict__ ge, int N) {
    int g = blockIdx.x, t = threadIdx.x;
    int lo = 0, hi = N;
    while (lo < hi) { int mid = (lo + hi) >> 1; if (n2g[mid] < g) lo = mid + 1; else hi = mid; }
    int start = lo;
    hi = N;
    while (lo < hi) { int mid = (lo + hi) >> 1; if (n2g[mid] < g + 1) lo = mid + 1; else hi = mid; }
    int end = lo;
    float acc = 0.0f;
    for (int n = start; n < end; ++n) acc += nr[(size_t)n * HDIM + t];
    ge[(size_t)g * HDIM + t] = acc;
}

// ============ fused graph head: pred[g] = relu(ge[g]@gh0^T + b0) . gh2 + b2 ============
__global__ __launch_bounds__(256) void graph_head(
    const float* __restrict__ ge,              // [G][256]
    const float* __restrict__ w0, const float* __restrict__ b0,
    const float* __restrict__ w2, const float* __restrict__ b2,
    float* __restrict__ pred, int G)
{
    int g = blockIdx.x;
    if (g >= G) return;
    __shared__ float xs[256];
    __shared__ float ys[256];
    int t = threadIdx.x;
    xs[t] = ge[(size_t)g * 256 + t];
    __syncthreads();
    float acc = b0[t];
    const float* wr = w0 + (size_t)t * 256;
    #pragma unroll 8
    for (int k = 0; k < 256; ++k) acc = fmaf(wr[k], xs[k], acc);
    ys[t] = fmaxf(acc, 0.0f) * w2[t];
    __syncthreads();
    for (int o = 128; o > 0; o >>= 1) {
        if (t < o) ys[t] += ys[t + o];
        __syncthreads();
    }
    if (t == 0) pred[g] = ys[0] + b2[0];
}

extern "C" void kernel_launch(void* const* d_in, const int* in_sizes, int n_in,
                              void* d_out, int out_size, void* d_ws, size_t ws_size,
                              hipStream_t stream) {
    const float* atom_feats   = (const float*)d_in[0];
    const float* edge_feats   = (const float*)d_in[1];
    const float* edge_weights = (const float*)d_in[2];
    const float* Wi    = (const float*)d_in[3];
    const float* Wm_w  = (const float*)d_in[4];
    const float* Wm_b  = (const float*)d_in[5];
    const float* Wn_w  = (const float*)d_in[6];
    const float* Wn_b  = (const float*)d_in[7];
    const float* nh0_w = (const float*)d_in[8];
    const float* nh0_b = (const float*)d_in[9];
    const float* nh2_w = (const float*)d_in[10];
    const float* nh2_b = (const float*)d_in[11];
    const float* eh0_w = (const float*)d_in[12];
    const float* eh0_b = (const float*)d_in[13];
    const float* eh2_w = (const float*)d_in[14];
    const float* eh2_b = (const float*)d_in[15];
    const float* gh0_w = (const float*)d_in[16];
    const float* gh0_b = (const float*)d_in[17];
    const float* gh2_w = (const float*)d_in[18];
    const float* gh2_b = (const float*)d_in[19];
    const int* edge_src      = (const int*)d_in[20];
    const int* edge_dst      = (const int*)d_in[21];
    // d_in[22]=b2rev: always e^1 and valid; unused.
    const int* node_to_graph = (const int*)d_in[23];

    int N = in_sizes[0] / ATOMF;
    int E = in_sizes[1] / BONDF;
    long long G = ((long long)out_size - (long long)N * (ATOMF + HDIM)
                   - (long long)E * (BONDF + HDIM)) / (1 + HDIM);

    // d_out slices
    float* out = (float*)d_out;
    float* pred_node = out;
    float* pred_edge = pred_node + (size_t)N * ATOMF;
    float* pred_grph = pred_edge + (size_t)E * BONDF;
    float* gemb      = pred_grph + (size_t)G;
    float* node_repr = gemb + (size_t)G * HDIM;
    float* h_f32     = node_repr + (size_t)N * HDIM;

    // workspace layout (single h buffer: in-place update keeps loop working set ~L3-sized)
    unsigned short* hA    = (unsigned short*)d_ws;      // E*256
    unsigned short* nrb   = hA + (size_t)E * HDIM;      // N*256 (node_repr bf16)
    unsigned short* Mb    = nrb + (size_t)N * HDIM;     // N*256
    unsigned short* atomb = Mb + (size_t)N * HDIM;      // N*160
    unsigned short* Wib   = atomb + (size_t)N * 160;
    unsigned short* Wmb   = Wib + 256 * 160;
    unsigned short* Wnb   = Wmb + 256 * 256;
    unsigned short* nh0b  = Wnb + 256 * KWN;
    unsigned short* nh2b  = nh0b + 256 * 256;
    unsigned short* eh0b  = nh2b + 256 * 256;
    unsigned short* eh2b  = eh0b + 256 * 256;
    int* csr = (int*)(eh2b + 256 * 256);
    int* cnt    = csr;
    int* off    = cnt + N;
    int* cursor = off + N + 1;
    int* elist  = cursor + N;
    int* csum   = elist + E;
    int* coff   = csum + 1024;

    int nchunks = (N + SCAN_CHUNK - 1) / SCAN_CHUNK;

    // ---- CSR build (per launch; deterministic via sort) ----
    hipMemsetAsync(cnt, 0, (size_t)N * sizeof(int), stream);
    count_dst<<<(E + 255) / 256, 256, 0, stream>>>(edge_dst, cnt, E);
    scan_reduce<<<nchunks, 256, 0, stream>>>(cnt, csum, N);
    scan_sums<<<1, 1024, 0, stream>>>(csum, coff, nchunks);
    scan_apply<<<nchunks, 256, 0, stream>>>(cnt, coff, off, cursor, N);
    fill_elist<<<(E + 255) / 256, 256, 0, stream>>>(edge_dst, cursor, elist, E);
    sort_buckets<<<(N + 255) / 256, 256, 0, stream>>>(off, elist, N);

    // ---- weight conversion + atom pre-convert ----
    pad_all<<<7 * 256, 256, 0, stream>>>(Wi, Wm_w, Wn_w, nh0_w, nh2_w, eh0_w, eh2_w,
                                         Wib, Wmb, Wnb, nh0b, nh2b, eh0b, eh2b);
    atom_conv<<<(N + 3) / 4, 640, 0, stream>>>(atom_feats, atomb, N);

    // ---- 1) h0 = relu([atom[src], bond] @ Wi^T) -> hA ----
    mfma_gemm_cat<<<(E + 127) / 128, 512, 0, stream>>>(atomb, edge_feats, edge_src,
                                                       E, Wib, hA);

    // ---- 2) message-passing loop: gather_M + fused msg-GEMM, h updated IN PLACE ----
    int ngrid = (N + 3) / 4;
    for (int d = 0; d < DEPTH_HC; ++d) {
        gather_M<<<ngrid, 256, 0, stream>>>(hA, edge_weights, off, elist, Mb, N);
        float* cf = (d == DEPTH_HC - 1) ? h_f32 : nullptr;
        mfma_gemm_msg<<<(E + 127) / 128, 512, 0, stream>>>(
            Mb, hA, edge_weights, edge_src, E, Wmb, Wm_b, cf);
    }

    // ---- 3) edge head: fused 2-layer, writes pred_edge directly ----
    head_fused<<<(E + 127) / 128, 512, 0, stream>>>(hA, E, eh0b, eh0_b, eh2b, eh2_b,
                                                    pred_edge, BONDF);

    // ---- 4) node_agg (gather) + fused cat+Wn GEMM -> node_repr (f32 + bf16 into nrb) ----
    gather_M<<<ngrid, 256, 0, stream>>>(hA, edge_weights, off, elist, Mb, N);
    mfma_gemm_catwn<<<(N + 127) / 128, 512, 0, stream>>>(atomb, Mb, N, Wnb, Wn_b,
                                                         node_repr, nrb);

    // ---- 5) graph embeds ----
    graph_sum<<<(int)G, HDIM, 0, stream>>>(node_repr, node_to_graph, gemb, N);

    // ---- 6) node head: fused 2-layer, writes pred_node directly ----
    head_fused<<<(N + 127) / 128, 512, 0, stream>>>(nrb, N, nh0b, nh0_b, nh2b, nh2_b,
                                                    pred_node, ATOMF);

    // ---- 7) graph head (fused 2-layer, one dispatch) ----
    graph_head<<<(int)G, 256, 0, stream>>>(gemb, gh0_w, gh0_b, gh2_w, gh2_b,
                                           pred_grph, (int)G);
}